// Round 13
// baseline (57.412 us; speedup 1.0000x reference)
//
#include <hip/hip_runtime.h>

// ContrastiveLoss: ys [4096,2048] f32, labels [4096] i32 -> scalar f32
// loss = mean over strict lower triangle of: same ? relu(2-cos)^2 : cos^2
// cos = pairwise cosine similarity of rows of ys (norm clamped at 1e-6).
//
// Round-13: LDS-free gram. yn (fp8) is repacked fragment-major:
//   pack[g][kb][row][b]  (g=row/16, kb=k/32, row=k%.., 32B per row-slot)
// so a wave's MFMA fragment load is 12 coalesced dwordx4 from L2/L3 --
// no LDS, no barriers, no vmcnt in the K-loop; waves free-run and the
// compiler pipelines loads across unrolled iterations. Geometry: 1056
// blocks (128x64 lower-tri tiles), 4 waves of 64x32, MX K=128 MFMA.

#define ROWS 4096
#define KDIM 2048
// 128-row x 64-col tiles: bi in [0,32), bj <= 2*bi+1 -> 1056 jobs.
#define NJOBS 1056
#define NSTEPS 16           // K-steps of 128
#define FSCALE 32.0f        // fp8 pre-scale
#define FSCALE2_INV (1.0f / (FSCALE * FSCALE))
#define SCALE_ONE 0x7F7F7F7F  // E8M0 exponent 127 -> 2^0 in every byte
#define GRPSZ 32768         // bytes per 16-row packed group (16*2048)

typedef float f32x4 __attribute__((ext_vector_type(4)));
typedef int i32x4 __attribute__((ext_vector_type(4)));
typedef int i32x8 __attribute__((ext_vector_type(8)));

// ---------------- Kernel 1: row normalize, f32 -> fp8 e4m3 (x32) ----------
__global__ __launch_bounds__(256) void normalize_rows(
    const float* __restrict__ ys, unsigned int* __restrict__ yn) {
    int row = blockIdx.x;
    const float4* src = (const float4*)(ys + (size_t)row * KDIM);
    float4 vals[2];
    float ss = 0.f;
#pragma unroll
    for (int i = 0; i < 2; ++i) {
        float4 v = src[threadIdx.x + i * 256];
        vals[i] = v;
        ss += v.x * v.x + v.y * v.y + v.z * v.z + v.w * v.w;
    }
#pragma unroll
    for (int off = 32; off > 0; off >>= 1) ss += __shfl_down(ss, off);
    __shared__ float red[4];
    int lane = threadIdx.x & 63, wv = threadIdx.x >> 6;
    if (lane == 0) red[wv] = ss;
    __syncthreads();
    float tot = red[0] + red[1] + red[2] + red[3];
    float inv = FSCALE / fmaxf(sqrtf(tot), 1e-6f);
    unsigned int* dst = yn + (size_t)row * (KDIM / 4);
#pragma unroll
    for (int i = 0; i < 2; ++i) {
        float4 v = vals[i];
        int p = __builtin_amdgcn_cvt_pk_fp8_f32(v.x * inv, v.y * inv, 0, false);
        p = __builtin_amdgcn_cvt_pk_fp8_f32(v.z * inv, v.w * inv, p, true);
        dst[threadIdx.x + i * 256] = (unsigned int)p;
    }
}

// ---------------- Kernel 1b: repack linear fp8 -> fragment-major ----------
// pack[g*32768 + kb*512 + row*32 + b] = yn[(g*16+row)*2048 + kb*32 + b]
// Write side: lanes 0..63 cover row*32+off = lane*8 -> 512B contiguous.
__global__ __launch_bounds__(256) void repack(
    const unsigned char* __restrict__ yn, unsigned char* __restrict__ pk) {
    int g = blockIdx.x;
    int tid = threadIdx.x, lane = tid & 63, w = tid >> 6;
    int row = lane >> 2, off = (lane & 3) * 8;
    const unsigned char* src = yn + (size_t)(g * 16 + row) * KDIM + off;
    unsigned char* dst = pk + (size_t)g * GRPSZ + row * 32 + off;
#pragma unroll
    for (int i = 0; i < 16; ++i) {
        int kb = i * 4 + w;
        *(unsigned long long*)(dst + kb * 512) =
            *(const unsigned long long*)(src + kb * 32);
    }
}

// ---------------- Kernel 2: LDS-free 128x64 Gram tile + fused loss --------
__global__ __launch_bounds__(256) void gram_loss(
    const unsigned char* __restrict__ pk, const int* __restrict__ labels,
    float* __restrict__ partials) {
    // XCD-chunk swizzle (bijective: 1056 % 8 == 0, 132 jobs per XCD):
    int t = (blockIdx.x & 7) * (NJOBS / 8) + (blockIdx.x >> 3);
    // job t -> (bi, bj): jobs for bi occupy [bi*(bi+1), bi*(bi+1)+2bi+2)
    int bi = (int)((sqrtf((float)(4 * t + 1)) - 1.0f) * 0.5f);
    while (bi * (bi + 1) > t) --bi;
    while ((bi + 1) * (bi + 2) <= t) ++bi;
    int bj = t - bi * (bi + 1);

    __shared__ int labI[128];
    __shared__ int labJ[64];
    __shared__ float red[4];

    int tid = threadIdx.x, lane = tid & 63, wv = tid >> 6;
    int wr = wv >> 1, wc = wv & 1;
    int rowA = bi * 128, rowB = bj * 64;

    if (tid < 128) labI[tid] = labels[rowA + tid];
    else if (tid < 192) labJ[tid - 128] = labels[rowB + tid - 128];

    int colB = lane & 15;  // spatial index within 16x16 fragment
    int kq = lane >> 4;    // k-quarter: lane holds k = 32*kq .. +31

    // Per-lane fragment bases: group g = row/16; lane offset kq*512+colB*32.
    size_t laneoff = (size_t)kq * 512 + colB * 32;
    const unsigned char* baseA = pk + (size_t)(bi * 8 + wr * 4) * GRPSZ + laneoff;
    const unsigned char* baseB = pk + (size_t)(bj * 4 + wc * 2) * GRPSZ + laneoff;

    f32x4 zero = {0.f, 0.f, 0.f, 0.f};
    f32x4 acc[4][2];
#pragma unroll
    for (int m = 0; m < 4; ++m)
#pragma unroll
        for (int n = 0; n < 2; ++n) acc[m][n] = zero;

#pragma unroll 2
    for (int ts = 0; ts < NSTEPS; ++ts) {
        size_t ko = (size_t)ts * 2048;  // (ts*4 k-blocks) * 512B
        i32x8 af8[4];
#pragma unroll
        for (int m = 0; m < 4; ++m) {
            const unsigned char* p = baseA + (size_t)m * GRPSZ + ko;
            i32x4 lo = *(const i32x4*)p;
            i32x4 hi = *(const i32x4*)(p + 16);
            af8[m] = (i32x8){lo.x, lo.y, lo.z, lo.w, hi.x, hi.y, hi.z, hi.w};
        }
#pragma unroll
        for (int n = 0; n < 2; ++n) {
            const unsigned char* p = baseB + (size_t)n * GRPSZ + ko;
            i32x4 lo = *(const i32x4*)p;
            i32x4 hi = *(const i32x4*)(p + 16);
            i32x8 bn = (i32x8){lo.x, lo.y, lo.z, lo.w, hi.x, hi.y, hi.z, hi.w};
#pragma unroll
            for (int m = 0; m < 4; ++m)
                acc[m][n] = __builtin_amdgcn_mfma_scale_f32_16x16x128_f8f6f4(
                    af8[m], bn, acc[m][n],
                    0, 0,                  // cbsz=fp8, blgp=fp8
                    0, SCALE_ONE,          // opsel_a, scale_a (1.0)
                    0, SCALE_ONE);         // opsel_b, scale_b (1.0)
        }
    }

    __syncthreads();  // labels visible

    // fused loss epilogue: ti = wr*64+m*16+kq*4+j, tj = wc*32+n*16+colB
    float lsum = 0.f;
#pragma unroll
    for (int m = 0; m < 4; ++m) {
#pragma unroll
        for (int n = 0; n < 2; ++n) {
#pragma unroll
            for (int j = 0; j < 4; ++j) {
                int ti = wr * 64 + m * 16 + kq * 4 + j;
                int tj = wc * 32 + n * 16 + colB;
                int gi = rowA + ti, gj = rowB + tj;
                if (gi > gj) {
                    float c = acc[m][n][j] * FSCALE2_INV;
                    float v = (labI[ti] == labJ[tj]) ? fmaxf(2.0f - c, 0.0f) : c;
                    lsum += v * v;
                }
            }
        }
    }
#pragma unroll
    for (int off = 32; off > 0; off >>= 1) lsum += __shfl_down(lsum, off);
    if (lane == 0) red[wv] = lsum;
    __syncthreads();
    if (tid == 0) partials[blockIdx.x] = red[0] + red[1] + red[2] + red[3];
}

// ---------------- Kernel 3: deterministic final reduction -----------------
__global__ __launch_bounds__(256) void finalize(
    const float* __restrict__ partials, float* __restrict__ out) {
    float s = 0.f;
    for (int i = threadIdx.x; i < NJOBS; i += 256) s += partials[i];
#pragma unroll
    for (int off = 32; off > 0; off >>= 1) s += __shfl_down(s, off);
    __shared__ float red[4];
    int lane = threadIdx.x & 63, wv = threadIdx.x >> 6;
    if (lane == 0) red[wv] = s;
    __syncthreads();
    if (threadIdx.x == 0) {
        const double npair = (double)ROWS * (ROWS - 1) / 2.0;
        out[0] = (float)((double)(red[0] + red[1] + red[2] + red[3]) / npair);
    }
}

extern "C" void kernel_launch(void* const* d_in, const int* in_sizes, int n_in,
                              void* d_out, int out_size, void* d_ws, size_t ws_size,
                              hipStream_t stream) {
    const float* ys = (const float*)d_in[0];
    const int* labels = (const int*)d_in[1];
    float* out = (float*)d_out;

    unsigned char* yn = (unsigned char*)d_ws;                          // 8 MB fp8 linear
    unsigned char* pkb = (unsigned char*)d_ws + (size_t)ROWS * KDIM;   // 8 MB packed
    float* partials = (float*)((char*)d_ws + 2 * (size_t)ROWS * KDIM); // 4.2 KB

    normalize_rows<<<ROWS, 256, 0, stream>>>(ys, (unsigned int*)yn);
    repack<<<ROWS / 16, 256, 0, stream>>>(yn, pkb);
    gram_loss<<<NJOBS, 256, 0, stream>>>(pkb, labels, partials);
    finalize<<<1, 256, 0, stream>>>(partials, out);
}

// Round 14
// 47.580 us; speedup vs baseline: 1.2067x; 1.2067x over previous
//
#include <hip/hip_runtime.h>

// ContrastiveLoss: ys [4096,2048] f32, labels [4096] i32 -> scalar f32
// loss = mean over strict lower triangle of: same ? relu(2-cos)^2 : cos^2
// cos = pairwise cosine similarity of rows of ys (norm clamped at 1e-6).
//
// FINAL (= round-11, measured best 46.63 us total): r6 geometry (128x64
// tiles, 1056 blocks, 4 waves of 64x32 -- measured-best TLP point across
// 8 structural variants) + counted-vmcnt double-buffer schedule (raw
// s_barrier, s_waitcnt vmcnt(6), unroll 1, flat per-wave stage pointers).
// fp8-e4m3 staging (x32 pre-scale), MX-scaled K=128 MFMA (unit scales),
// XOR-swizzled LDS, fused loss epilogue, deterministic reduction.

#define ROWS 4096
#define KDIM 2048
// 128-row x 64-col tiles over the lower triangle: bi in [0,32), bj in
// [0,64); keep bj <= 2*bi+1 -> sum(2bi+2) = 1056 jobs.
#define NJOBS 1056
#define BK 128              // k-elements (= bytes) per K-step
#define NSTEPS (KDIM / BK)  // 16
#define FSCALE 32.0f        // fp8 pre-scale
#define FSCALE2_INV (1.0f / (FSCALE * FSCALE))
#define SCALE_ONE 0x7F7F7F7F  // E8M0 exponent 127 -> 2^0 in every byte

typedef float f32x4 __attribute__((ext_vector_type(4)));
typedef int i32x4 __attribute__((ext_vector_type(4)));
typedef int i32x8 __attribute__((ext_vector_type(8)));

__device__ __forceinline__ void async_copy16(const unsigned char* g, unsigned char* l) {
    __builtin_amdgcn_global_load_lds(
        (const __attribute__((address_space(1))) void*)g,
        (__attribute__((address_space(3))) void*)l,
        16, 0, 0);
}

// ---------------- Kernel 1: row normalize, f32 -> fp8 e4m3 (x32) ----------
__global__ __launch_bounds__(256) void normalize_rows(
    const float* __restrict__ ys, unsigned int* __restrict__ yn) {
    int row = blockIdx.x;
    const float4* src = (const float4*)(ys + (size_t)row * KDIM);
    float4 vals[2];
    float ss = 0.f;
#pragma unroll
    for (int i = 0; i < 2; ++i) {
        float4 v = src[threadIdx.x + i * 256];
        vals[i] = v;
        ss += v.x * v.x + v.y * v.y + v.z * v.z + v.w * v.w;
    }
#pragma unroll
    for (int off = 32; off > 0; off >>= 1) ss += __shfl_down(ss, off);
    __shared__ float red[4];
    int lane = threadIdx.x & 63, wv = threadIdx.x >> 6;
    if (lane == 0) red[wv] = ss;
    __syncthreads();
    float tot = red[0] + red[1] + red[2] + red[3];
    float inv = FSCALE / fmaxf(sqrtf(tot), 1e-6f);
    unsigned int* dst = yn + (size_t)row * (KDIM / 4);
#pragma unroll
    for (int i = 0; i < 2; ++i) {
        float4 v = vals[i];
        int p = __builtin_amdgcn_cvt_pk_fp8_f32(v.x * inv, v.y * inv, 0, false);
        p = __builtin_amdgcn_cvt_pk_fp8_f32(v.z * inv, v.w * inv, p, true);
        dst[threadIdx.x + i * 256] = (unsigned int)p;
    }
}

// ---------------- Kernel 2: 128x64 Gram tile + fused loss -----------------
// Per-wave staging: wave wv covers A chunks {wv, wv+4, wv+8, wv+12} and
// B chunks {16+wv, 20+wv}: 6 global_load_lds per wave per tile.
__device__ __forceinline__ void stage_tile(
    const unsigned char* pA, const unsigned char* pB, int k0,
    unsigned char* As, unsigned char* Bs, int wv) {
#pragma unroll
    for (int it = 0; it < 4; ++it)
        async_copy16(pA + (size_t)it * 32 * KDIM + k0, As + (it * 4 + wv) * 1024);
#pragma unroll
    for (int it = 0; it < 2; ++it)
        async_copy16(pB + (size_t)it * 32 * KDIM + k0, Bs + (it * 4 + wv) * 1024);
}

__device__ __forceinline__ void compute_step(
    const unsigned char* As, const unsigned char* Bs,
    f32x4 acc[4][2], int wr, int wc, int colB, int kq) {
    // Lane kq's 32 true-k bytes sit at granules 2kq, 2kq+1; staging's
    // inverse-XOR means addr0 and addr0^16 give ascending k order.
    i32x8 af8[4];
#pragma unroll
    for (int m = 0; m < 4; ++m) {
        int row = wr * 64 + m * 16 + colB;
        int byte0 = (row * BK + kq * 32) ^ ((row & 7) << 4);
        i32x4 lo = *(const i32x4*)(As + byte0);
        i32x4 hi = *(const i32x4*)(As + (byte0 ^ 16));
        af8[m] = (i32x8){lo.x, lo.y, lo.z, lo.w, hi.x, hi.y, hi.z, hi.w};
    }
#pragma unroll
    for (int n = 0; n < 2; ++n) {
        int row = wc * 32 + n * 16 + colB;
        int byte0 = (row * BK + kq * 32) ^ ((row & 7) << 4);
        i32x4 lo = *(const i32x4*)(Bs + byte0);
        i32x4 hi = *(const i32x4*)(Bs + (byte0 ^ 16));
        i32x8 bn = (i32x8){lo.x, lo.y, lo.z, lo.w, hi.x, hi.y, hi.z, hi.w};
#pragma unroll
        for (int m = 0; m < 4; ++m)
            acc[m][n] = __builtin_amdgcn_mfma_scale_f32_16x16x128_f8f6f4(
                af8[m], bn, acc[m][n],
                0, 0,                  // cbsz=fp8, blgp=fp8
                0, SCALE_ONE,          // opsel_a, scale_a (1.0)
                0, SCALE_ONE);         // opsel_b, scale_b (1.0)
    }
}

__global__ __launch_bounds__(256) void gram_loss(
    const unsigned char* __restrict__ yn, const int* __restrict__ labels,
    float* __restrict__ partials) {
    // XCD-chunk swizzle (bijective: 1056 % 8 == 0, 132 jobs per XCD):
    int t = (blockIdx.x & 7) * (NJOBS / 8) + (blockIdx.x >> 3);
    // job t -> (bi, bj): jobs for bi occupy [bi*(bi+1), bi*(bi+1)+2bi+2)
    int bi = (int)((sqrtf((float)(4 * t + 1)) - 1.0f) * 0.5f);
    while (bi * (bi + 1) > t) --bi;
    while ((bi + 1) * (bi + 2) <= t) ++bi;
    int bj = t - bi * (bi + 1);

    __shared__ __attribute__((aligned(16))) unsigned char As[2][128 * BK];  // 2x16KB
    __shared__ __attribute__((aligned(16))) unsigned char Bs[2][64 * BK];   // 2x8KB
    __shared__ int labI[128];
    __shared__ int labJ[64];
    __shared__ float red[4];

    int tid = threadIdx.x, lane = tid & 63, wv = tid >> 6;
    int wr = wv >> 1, wc = wv & 1;
    int rowA = bi * 128, rowB = bj * 64;

    if (tid < 128) labI[tid] = labels[rowA + tid];
    else if (tid < 192) labJ[tid - 128] = labels[rowB + tid - 128];

    // staging: lane covers row lane>>3; 16B granule (lane&7) pre-XORed with
    // row so linear global_load_lds writes land swizzled: byte^=((row&7)<<4).
    int srow = lane >> 3;
    int sbyte = ((lane & 7) ^ srow) * 16;
    const unsigned char* pA = yn + (size_t)(rowA + wv * 8 + srow) * KDIM + sbyte;
    const unsigned char* pB = yn + (size_t)(rowB + wv * 8 + srow) * KDIM + sbyte;

    f32x4 zero = {0.f, 0.f, 0.f, 0.f};
    f32x4 acc[4][2];
#pragma unroll
    for (int m = 0; m < 4; ++m)
#pragma unroll
        for (int n = 0; n < 2; ++n) acc[m][n] = zero;

    int colB = lane & 15;  // spatial index within 16x16 fragment
    int kq = lane >> 4;    // k-quarter: lane holds k = 32*kq .. +31

    // ---- counted-vmcnt double-buffer pipeline (16 K-steps) ----
    stage_tile(pA, pB, 0 * BK, As[0], Bs[0], wv);
    stage_tile(pA, pB, 1 * BK, As[1], Bs[1], wv);
    asm volatile("s_waitcnt vmcnt(6) lgkmcnt(0)" ::: "memory");  // tile0 + labels
    __builtin_amdgcn_s_barrier();

#pragma unroll 1
    for (int ts = 0; ts < NSTEPS - 2; ts += 2) {
        compute_step(As[0], Bs[0], acc, wr, wc, colB, kq);   // tile ts
        __builtin_amdgcn_s_barrier();                         // buf0 free
        stage_tile(pA, pB, (ts + 2) * BK, As[0], Bs[0], wv);
        asm volatile("s_waitcnt vmcnt(6)" ::: "memory");      // tile ts+1 landed
        __builtin_amdgcn_s_barrier();

        compute_step(As[1], Bs[1], acc, wr, wc, colB, kq);   // tile ts+1
        __builtin_amdgcn_s_barrier();                         // buf1 free
        stage_tile(pA, pB, (ts + 3) * BK, As[1], Bs[1], wv);
        asm volatile("s_waitcnt vmcnt(6)" ::: "memory");      // tile ts+2 landed
        __builtin_amdgcn_s_barrier();
    }
    compute_step(As[0], Bs[0], acc, wr, wc, colB, kq);       // tile 14
    __builtin_amdgcn_s_barrier();
    asm volatile("s_waitcnt vmcnt(0)" ::: "memory");          // tile 15 landed
    __builtin_amdgcn_s_barrier();
    compute_step(As[1], Bs[1], acc, wr, wc, colB, kq);       // tile 15

    // fused loss epilogue: ti = wr*64+m*16+kq*4+j, tj = wc*32+n*16+colB
    float lsum = 0.f;
#pragma unroll
    for (int m = 0; m < 4; ++m) {
#pragma unroll
        for (int n = 0; n < 2; ++n) {
#pragma unroll
            for (int j = 0; j < 4; ++j) {
                int ti = wr * 64 + m * 16 + kq * 4 + j;
                int tj = wc * 32 + n * 16 + colB;
                int gi = rowA + ti, gj = rowB + tj;
                if (gi > gj) {
                    float c = acc[m][n][j] * FSCALE2_INV;
                    float v = (labI[ti] == labJ[tj]) ? fmaxf(2.0f - c, 0.0f) : c;
                    lsum += v * v;
                }
            }
        }
    }
#pragma unroll
    for (int off = 32; off > 0; off >>= 1) lsum += __shfl_down(lsum, off);
    if (lane == 0) red[wv] = lsum;
    __syncthreads();
    if (tid == 0) partials[blockIdx.x] = red[0] + red[1] + red[2] + red[3];
}

// ---------------- Kernel 3: deterministic final reduction -----------------
__global__ __launch_bounds__(256) void finalize(
    const float* __restrict__ partials, float* __restrict__ out) {
    float s = 0.f;
    for (int i = threadIdx.x; i < NJOBS; i += 256) s += partials[i];
#pragma unroll
    for (int off = 32; off > 0; off >>= 1) s += __shfl_down(s, off);
    __shared__ float red[4];
    int lane = threadIdx.x & 63, wv = threadIdx.x >> 6;
    if (lane == 0) red[wv] = s;
    __syncthreads();
    if (threadIdx.x == 0) {
        const double npair = (double)ROWS * (ROWS - 1) / 2.0;
        out[0] = (float)((double)(red[0] + red[1] + red[2] + red[3]) / npair);
    }
}

extern "C" void kernel_launch(void* const* d_in, const int* in_sizes, int n_in,
                              void* d_out, int out_size, void* d_ws, size_t ws_size,
                              hipStream_t stream) {
    const float* ys = (const float*)d_in[0];
    const int* labels = (const int*)d_in[1];
    float* out = (float*)d_out;

    unsigned char* yn = (unsigned char*)d_ws;                        // 8 MB fp8
    float* partials = (float*)((char*)d_ws + (size_t)ROWS * KDIM);   // 4.2 KB

    normalize_rows<<<ROWS, 256, 0, stream>>>(ys, (unsigned int*)yn);
    gram_loss<<<NJOBS, 256, 0, stream>>>(yn, labels, partials);
    finalize<<<1, 256, 0, stream>>>(partials, out);
}